// Round 9
// baseline (41.552 us; speedup 1.0000x reference)
//
#include <hip/hip_runtime.h>
#include <hip/hip_bf16.h>

#define B_TOT 16384

typedef __bf16 bf16x8 __attribute__((ext_vector_type(8)));
typedef __bf16 bf16x4 __attribute__((ext_vector_type(4)));
typedef float  f32x4  __attribute__((ext_vector_type(4)));

// ---- workspace layout (bytes) ----
// wp0: [17 ksteps][8 nblk][64 lanes][8 bf16]  K-map: k<400 img, 400..415 zero, 416..543 Whh0
// wp1: [ 8 ksteps][8 nblk][64 lanes][8 bf16]  k<128 Wih1, 128..255 Whh1
// wph: [ 4 ksteps][64 lanes][8 bf16]          W_cls|W_act padded to N=16
#define NG0 (17*8*64)
#define NG1 (8*8*64)
#define NGH (4*64)
#define WP0_OFF  0
#define WP1_OFF  (NG0*16)
#define WPH_OFF  (WP1_OFF + NG1*16)
#define BIAS0_OFF (WPH_OFF + NGH*16)
#define BIAS1_OFF (BIAS0_OFF + 512)
#define BIASH_OFF (BIAS1_OFF + 512)
#define PREP_BLOCKS 53

__device__ __forceinline__ float fast_tanh(float x) {
    float cx = fminf(fmaxf(x, -9.f), 9.f);
    float t = __builtin_amdgcn_exp2f(cx * 2.8853900817779268f);
    return 1.f - 2.f * __builtin_amdgcn_rcpf(t + 1.f);
}

__device__ __forceinline__ bf16x8 load_cvt8(const float* __restrict__ p) {
    float4 a = *(const float4*)p;
    float4 b = *(const float4*)(p + 4);
    bf16x8 v;
    v[0]=(__bf16)a.x; v[1]=(__bf16)a.y; v[2]=(__bf16)a.z; v[3]=(__bf16)a.w;
    v[4]=(__bf16)b.x; v[5]=(__bf16)b.y; v[6]=(__bf16)b.z; v[7]=(__bf16)b.w;
    return v;
}

// ============ kernel 1: weight prepack (tiny, runs first) ============
__global__ __launch_bounds__(256) void prepack_kernel(
    const float* __restrict__ Wih0, const float* __restrict__ Whh0,
    const float* __restrict__ Wih1, const float* __restrict__ Whh1,
    const float* __restrict__ Wcls, const float* __restrict__ Wact,
    const float* __restrict__ bih0, const float* __restrict__ bhh0,
    const float* __restrict__ bih1, const float* __restrict__ bhh1,
    const float* __restrict__ bcls, const float* __restrict__ bact,
    char* __restrict__ ws)
{
    int idx = blockIdx.x * 256 + threadIdx.x;
    __bf16* wp0 = (__bf16*)(ws + WP0_OFF);
    __bf16* wp1 = (__bf16*)(ws + WP1_OFF);
    __bf16* wph = (__bf16*)(ws + WPH_OFF);
    float* bias0 = (float*)(ws + BIAS0_OFF);
    float* bias1 = (float*)(ws + BIAS1_OFF);
    float* biash = (float*)(ws + BIASH_OFF);

    if (idx < NG0) {
        int lane = idx & 63, g = idx >> 6, s = g >> 3, nb = g & 7;
        int n = nb * 16 + (lane & 15);
        int kb = s * 32 + (lane >> 4) * 8;
        bf16x8 v;
        #pragma unroll
        for (int j = 0; j < 8; ++j) {
            int k = kb + j;
            float x = 0.f;
            if (k < 400)       x = Wih0[n * 400 + k];
            else if (k >= 416) x = Whh0[n * 128 + (k - 416)];
            v[j] = (__bf16)x;
        }
        *(bf16x8*)(wp0 + (size_t)idx * 8) = v;
    } else if (idx < NG0 + NG1) {
        int i2 = idx - NG0;
        int lane = i2 & 63, g = i2 >> 6, s = g >> 3, nb = g & 7;
        int n = nb * 16 + (lane & 15);
        int kb = s * 32 + (lane >> 4) * 8;
        bf16x8 v;
        #pragma unroll
        for (int j = 0; j < 8; ++j) {
            int k = kb + j;
            float x = (k < 128) ? Wih1[n * 128 + k] : Whh1[n * 128 + (k - 128)];
            v[j] = (__bf16)x;
        }
        *(bf16x8*)(wp1 + (size_t)i2 * 8) = v;
    } else if (idx < NG0 + NG1 + NGH) {
        int i3 = idx - NG0 - NG1;
        int lane = i3 & 63, s = i3 >> 6;
        int n = lane & 15;
        int kb = s * 32 + (lane >> 4) * 8;
        bf16x8 v;
        #pragma unroll
        for (int j = 0; j < 8; ++j) {
            int k = kb + j;
            float x = 0.f;
            if (n < 10)      x = Wcls[n * 128 + k];
            else if (n < 12) x = Wact[(n - 10) * 128 + k];
            v[j] = (__bf16)x;
        }
        *(bf16x8*)(wph + (size_t)i3 * 8) = v;
    } else {
        int i4 = idx - NG0 - NG1 - NGH;
        if (i4 < 128) bias0[i4] = bih0[i4] + bhh0[i4];
        else if (i4 < 256) { int i = i4 - 128; bias1[i] = bih1[i] + bhh1[i]; }
        else if (i4 < 272) {
            int i = i4 - 256;
            biash[i] = (i < 10) ? bcls[i] : ((i < 12) ? bact[i - 10] : 0.f);
        }
    }
}

// ============ kernel 2: fused gather + GEMMs, MTILE=32, 8 waves ============
// LDS: xl[32][424]  (X-tile; 848B row stride = 80 mod 128 -> 2-way bank alias, free)
//      hex 2x[32][136] (h1/h2 exchange; 272B = 16 mod 128 -> spread)
#define XLSTR 424
#define HEXSTR 136

__global__ __launch_bounds__(512, 4) void fused_main(
    const float* __restrict__ image, const int* __restrict__ center,
    const float* __restrict__ h0, const char* __restrict__ ws,
    float* __restrict__ out)
{
    const bf16x8* wp0 = (const bf16x8*)(ws + WP0_OFF);
    const bf16x8* wp1 = (const bf16x8*)(ws + WP1_OFF);
    const bf16x8* wph = (const bf16x8*)(ws + WPH_OFF);
    const float* bias0 = (const float*)(ws + BIAS0_OFF);
    const float* bias1 = (const float*)(ws + BIAS1_OFF);
    const float* biash = (const float*)(ws + BIASH_OFF);

    __shared__ __align__(16) __bf16 xl[32 * XLSTR];
    __shared__ __align__(16) __bf16 hex[2 * 32 * HEXSTR];
    __bf16* h1ex = hex;
    __bf16* h2ex = hex + 32 * HEXSTR;

    const int t = threadIdx.x, lane = t & 63, wn = t >> 6;   // 8 waves
    const int m0 = blockIdx.x * 32;

    // ================= gather: wave-private, 4 samples per wave =================
    {
        const int s0 = wn * 4;                 // local sample base for this wave
        const int lr28 = lane / 28, lx28 = lane - lr28 * 28;  // lanes 56..63 idle

        int cx[4], cy[4], rlo[4], rhi[4];
        #pragma unroll
        for (int i = 0; i < 4; ++i) {
            cx[i] = center[(m0 + s0 + i) * 2 + 0];
            cy[i] = center[(m0 + s0 + i) * 2 + 1];
            rlo[i] = max(0, cy[i] - 20);
            rhi[i] = min(28, cy[i]);
        }

        // zero this wave's 4 LDS rows (424 elems = 53 lanes x 16B)
        #pragma unroll
        for (int i = 0; i < 4; ++i) {
            if (lane < 53) {
                f32x4 z = {};
                *(f32x4*)(xl + (s0 + i) * XLSTR + lane * 8) = z;
            }
        }

        // issue all 40 coalesced row loads (2 rows x 28 lanes per iter)
        float gv[4][10];
        #pragma unroll
        for (int i = 0; i < 4; ++i) {
            const float* img = image + (size_t)(m0 + s0 + i) * 784;
            #pragma unroll
            for (int it = 0; it < 10; ++it) {
                int iy = rlo[i] + lr28 + it * 2;
                gv[i][it] = (lr28 < 2 && iy < rhi[i]) ? img[iy * 28 + lx28] : 0.f;
            }
        }
        // scatter into xl (k = r*20 + c)
        #pragma unroll
        for (int i = 0; i < 4; ++i) {
            __bf16* dst = xl + (s0 + i) * XLSTR;
            #pragma unroll
            for (int it = 0; it < 10; ++it) {
                int iy = rlo[i] + lr28 + it * 2;
                int r = iy - (cy[i] - 20), c = lx28 - (cx[i] - 20);
                if (lr28 < 2 && iy < rhi[i] && (unsigned)c < 20u)
                    dst[r * 20 + c] = (__bf16)gv[i][it];
            }
        }
    }
    __syncthreads();

    // ================= GEMMs =================
    const int g = wn & 1, cg = wn >> 1;     // row group (16 rows), col group (32 cols)
    const int qr = lane >> 4, lr = lane & 15;
    const int arow = m0 + g * 16 + lr;

    const __bf16* xrow = xl + (g * 16 + lr) * XLSTR + qr * 8;
    const float* h0r0 = h0 + (size_t)arow * 128 + qr * 8;
    const float* h0r1 = h0r0 + (size_t)B_TOT * 128;

    float* outh1 = out + (size_t)B_TOT * 12;
    float* outh2 = out + (size_t)B_TOT * 140;

    // GEMM0: crop (k-steps 0..12 from LDS) + h0_0 (13..16 from global f32)
    f32x4 acc0[2] = {};
    #pragma unroll 4
    for (int s = 0; s < 13; ++s) {
        bf16x8 a  = *(const bf16x8*)(xrow + s * 32);
        bf16x8 b0 = wp0[(size_t)(s * 8 + cg * 2 + 0) * 64 + lane];
        bf16x8 b1 = wp0[(size_t)(s * 8 + cg * 2 + 1) * 64 + lane];
        acc0[0] = __builtin_amdgcn_mfma_f32_16x16x32_bf16(a, b0, acc0[0], 0, 0, 0);
        acc0[1] = __builtin_amdgcn_mfma_f32_16x16x32_bf16(a, b1, acc0[1], 0, 0, 0);
    }
    #pragma unroll
    for (int s = 0; s < 4; ++s) {
        bf16x8 a  = load_cvt8(h0r0 + s * 32);
        bf16x8 b0 = wp0[(size_t)((13 + s) * 8 + cg * 2 + 0) * 64 + lane];
        bf16x8 b1 = wp0[(size_t)((13 + s) * 8 + cg * 2 + 1) * 64 + lane];
        acc0[0] = __builtin_amdgcn_mfma_f32_16x16x32_bf16(a, b0, acc0[0], 0, 0, 0);
        acc0[1] = __builtin_amdgcn_mfma_f32_16x16x32_bf16(a, b1, acc0[1], 0, 0, 0);
    }
    #pragma unroll
    for (int f = 0; f < 2; ++f) {
        int n = cg * 32 + f * 16 + lr;
        float bv = bias0[n];
        #pragma unroll
        for (int r = 0; r < 4; ++r)
            h1ex[(g * 16 + qr * 4 + r) * HEXSTR + n] = (__bf16)fast_tanh(acc0[f][r] + bv);
    }

    // GEMM1 part A: h0_1 contribution (k-steps 4..7) — independent of h1
    f32x4 acc1[2] = {};
    #pragma unroll
    for (int s = 0; s < 4; ++s) {
        bf16x8 a  = load_cvt8(h0r1 + s * 32);
        bf16x8 b0 = wp1[(size_t)((4 + s) * 8 + cg * 2 + 0) * 64 + lane];
        bf16x8 b1 = wp1[(size_t)((4 + s) * 8 + cg * 2 + 1) * 64 + lane];
        acc1[0] = __builtin_amdgcn_mfma_f32_16x16x32_bf16(a, b0, acc1[0], 0, 0, 0);
        acc1[1] = __builtin_amdgcn_mfma_f32_16x16x32_bf16(a, b1, acc1[1], 0, 0, 0);
    }
    __syncthreads();

    // h1 full-line out stores: 32 rows x 128 cols, 8 cols/thread
    {
        int row = t >> 4, c0 = (t & 15) * 8;
        bf16x8 hv = *(const bf16x8*)(h1ex + row * HEXSTR + c0);
        float4 o1, o2;
        o1.x=(float)hv[0]; o1.y=(float)hv[1]; o1.z=(float)hv[2]; o1.w=(float)hv[3];
        o2.x=(float)hv[4]; o2.y=(float)hv[5]; o2.z=(float)hv[6]; o2.w=(float)hv[7];
        *(float4*)(outh1 + (size_t)(m0 + row) * 128 + c0) = o1;
        *(float4*)(outh1 + (size_t)(m0 + row) * 128 + c0 + 4) = o2;
    }

    // GEMM1 part B: h1 contribution (k-steps 0..3) from LDS
    {
        const __bf16* h1row = h1ex + (g * 16 + lr) * HEXSTR + qr * 8;
        #pragma unroll
        for (int s = 0; s < 4; ++s) {
            bf16x8 a  = *(const bf16x8*)(h1row + s * 32);
            bf16x8 b0 = wp1[(size_t)(s * 8 + cg * 2 + 0) * 64 + lane];
            bf16x8 b1 = wp1[(size_t)(s * 8 + cg * 2 + 1) * 64 + lane];
            acc1[0] = __builtin_amdgcn_mfma_f32_16x16x32_bf16(a, b0, acc1[0], 0, 0, 0);
            acc1[1] = __builtin_amdgcn_mfma_f32_16x16x32_bf16(a, b1, acc1[1], 0, 0, 0);
        }
    }
    #pragma unroll
    for (int f = 0; f < 2; ++f) {
        int n = cg * 32 + f * 16 + lr;
        float bv = bias1[n];
        #pragma unroll
        for (int r = 0; r < 4; ++r)
            h2ex[(g * 16 + qr * 4 + r) * HEXSTR + n] = (__bf16)fast_tanh(acc1[f][r] + bv);
    }
    __syncthreads();

    // h2 full-line out stores
    {
        int row = t >> 4, c0 = (t & 15) * 8;
        bf16x8 hv = *(const bf16x8*)(h2ex + row * HEXSTR + c0);
        float4 o1, o2;
        o1.x=(float)hv[0]; o1.y=(float)hv[1]; o1.z=(float)hv[2]; o1.w=(float)hv[3];
        o2.x=(float)hv[4]; o2.y=(float)hv[5]; o2.z=(float)hv[6]; o2.w=(float)hv[7];
        *(float4*)(outh2 + (size_t)(m0 + row) * 128 + c0) = o1;
        *(float4*)(outh2 + (size_t)(m0 + row) * 128 + c0 + 4) = o2;
    }

    // heads: waves with cg==0 (wn 0,1) cover both row groups
    if (cg == 0) {
        f32x4 acc2 = {};
        const __bf16* h2row = h2ex + (g * 16 + lr) * HEXSTR + qr * 8;
        #pragma unroll
        for (int s = 0; s < 4; ++s) {
            bf16x8 a = *(const bf16x8*)(h2row + s * 32);
            bf16x8 b = wph[(size_t)s * 64 + lane];
            acc2 = __builtin_amdgcn_mfma_f32_16x16x32_bf16(a, b, acc2, 0, 0, 0);
        }
        float bhd = biash[lr];
        #pragma unroll
        for (int r = 0; r < 4; ++r) {
            int mg = m0 + g * 16 + qr * 4 + r;
            float v = acc2[r] + bhd;
            if (lr < 10)      out[(size_t)mg * 10 + lr] = v;
            else if (lr < 12) out[(size_t)B_TOT * 10 + (size_t)mg * 2 + (lr - 10)] = v;
        }
    }
}

extern "C" void kernel_launch(void* const* d_in, const int* in_sizes, int n_in,
                              void* d_out, int out_size, void* d_ws, size_t ws_size,
                              hipStream_t stream) {
    const float* image = (const float*)d_in[0];
    const int*   center = (const int*)d_in[1];
    const float* h0   = (const float*)d_in[2];
    const float* Wih0 = (const float*)d_in[3];
    const float* bih0 = (const float*)d_in[4];
    const float* Whh0 = (const float*)d_in[5];
    const float* bhh0 = (const float*)d_in[6];
    const float* Wih1 = (const float*)d_in[7];
    const float* bih1 = (const float*)d_in[8];
    const float* Whh1 = (const float*)d_in[9];
    const float* bhh1 = (const float*)d_in[10];
    const float* Wcls = (const float*)d_in[11];
    const float* bcls = (const float*)d_in[12];
    const float* Wact = (const float*)d_in[13];
    const float* bact = (const float*)d_in[14];

    prepack_kernel<<<PREP_BLOCKS, 256, 0, stream>>>(
        Wih0, Whh0, Wih1, Whh1, Wcls, Wact,
        bih0, bhh0, bih1, bhh1, bcls, bact, (char*)d_ws);
    fused_main<<<B_TOT / 32, 512, 0, stream>>>(
        image, center, h0, (const char*)d_ws, (float*)d_out);
}

// Round 10
// 29.079 us; speedup vs baseline: 1.4289x; 1.4289x over previous
//
#include <hip/hip_runtime.h>
#include <hip/hip_bf16.h>

#define B_TOT 16384
#define MTILE 16

typedef __bf16 bf16x8 __attribute__((ext_vector_type(8)));
typedef float  f32x4  __attribute__((ext_vector_type(4)));

// ---- workspace layout (bytes) ----
// wp0: [17 ksteps][8 nblk][64 lanes][8 bf16]  K-map: k<400 crop, 400..415 zero, 416..543 Whh0
// wp1: [ 8 ksteps][8 nblk][64 lanes][8 bf16]  k<128 Wih1, 128..255 Whh1
// wph: [ 4 ksteps][64 lanes][8 bf16]          W_cls|W_act padded to N=16
#define NG0 (17*8*64)
#define NG1 (8*8*64)
#define NGH (4*64)
#define WP0_OFF  0
#define WP1_OFF  (NG0*16)
#define WPH_OFF  (WP1_OFF + NG1*16)
#define BIAS0_OFF (WPH_OFF + NGH*16)
#define BIAS1_OFF (BIAS0_OFF + 512)
#define BIASH_OFF (BIAS1_OFF + 512)
#define ZERO_OFF  (BIASH_OFF + 512)      // 256 B of zeros (OOB redirect target)
#define PREP_BLOCKS 53

__device__ __forceinline__ float fast_tanh(float x) {
    float cx = fminf(fmaxf(x, -9.f), 9.f);
    float t = __builtin_amdgcn_exp2f(cx * 2.8853900817779268f);
    return 1.f - 2.f * __builtin_amdgcn_rcpf(t + 1.f);
}

// fire-and-forget global->LDS (no VGPR destination; compiler cannot serialize)
__device__ __forceinline__ void gl_lds4(const float* g, void* l) {
    __builtin_amdgcn_global_load_lds((const __attribute__((address_space(1))) void*)g,
                                     (__attribute__((address_space(3))) void*)l, 4, 0, 0);
}
__device__ __forceinline__ void gl_lds16(const float* g, void* l) {
    __builtin_amdgcn_global_load_lds((const __attribute__((address_space(1))) void*)g,
                                     (__attribute__((address_space(3))) void*)l, 16, 0, 0);
}

__device__ __forceinline__ bf16x8 cvt8(f32x4 a, f32x4 b) {
    bf16x8 v;
    v[0]=(__bf16)a.x; v[1]=(__bf16)a.y; v[2]=(__bf16)a.z; v[3]=(__bf16)a.w;
    v[4]=(__bf16)b.x; v[5]=(__bf16)b.y; v[6]=(__bf16)b.z; v[7]=(__bf16)b.w;
    return v;
}

// ============ kernel 1: weight prepack + zero-buffer ============
__global__ __launch_bounds__(256) void prepack_kernel(
    const float* __restrict__ Wih0, const float* __restrict__ Whh0,
    const float* __restrict__ Wih1, const float* __restrict__ Whh1,
    const float* __restrict__ Wcls, const float* __restrict__ Wact,
    const float* __restrict__ bih0, const float* __restrict__ bhh0,
    const float* __restrict__ bih1, const float* __restrict__ bhh1,
    const float* __restrict__ bcls, const float* __restrict__ bact,
    char* __restrict__ ws)
{
    int idx = blockIdx.x * 256 + threadIdx.x;
    __bf16* wp0 = (__bf16*)(ws + WP0_OFF);
    __bf16* wp1 = (__bf16*)(ws + WP1_OFF);
    __bf16* wph = (__bf16*)(ws + WPH_OFF);
    float* bias0 = (float*)(ws + BIAS0_OFF);
    float* bias1 = (float*)(ws + BIAS1_OFF);
    float* biash = (float*)(ws + BIASH_OFF);

    if (idx < NG0) {
        int lane = idx & 63, g = idx >> 6, s = g >> 3, nb = g & 7;
        int n = nb * 16 + (lane & 15);
        int kb = s * 32 + (lane >> 4) * 8;
        bf16x8 v;
        #pragma unroll
        for (int j = 0; j < 8; ++j) {
            int k = kb + j;
            float x = 0.f;
            if (k < 400)       x = Wih0[n * 400 + k];
            else if (k >= 416) x = Whh0[n * 128 + (k - 416)];
            v[j] = (__bf16)x;
        }
        *(bf16x8*)(wp0 + (size_t)idx * 8) = v;
    } else if (idx < NG0 + NG1) {
        int i2 = idx - NG0;
        int lane = i2 & 63, g = i2 >> 6, s = g >> 3, nb = g & 7;
        int n = nb * 16 + (lane & 15);
        int kb = s * 32 + (lane >> 4) * 8;
        bf16x8 v;
        #pragma unroll
        for (int j = 0; j < 8; ++j) {
            int k = kb + j;
            float x = (k < 128) ? Wih1[n * 128 + k] : Whh1[n * 128 + (k - 128)];
            v[j] = (__bf16)x;
        }
        *(bf16x8*)(wp1 + (size_t)i2 * 8) = v;
    } else if (idx < NG0 + NG1 + NGH) {
        int i3 = idx - NG0 - NG1;
        int lane = i3 & 63, s = i3 >> 6;
        int n = lane & 15;
        int kb = s * 32 + (lane >> 4) * 8;
        bf16x8 v;
        #pragma unroll
        for (int j = 0; j < 8; ++j) {
            int k = kb + j;
            float x = 0.f;
            if (n < 10)      x = Wcls[n * 128 + k];
            else if (n < 12) x = Wact[(n - 10) * 128 + k];
            v[j] = (__bf16)x;
        }
        *(bf16x8*)(wph + (size_t)i3 * 8) = v;
    } else {
        int i4 = idx - NG0 - NG1 - NGH;
        if (i4 < 128) bias0[i4] = bih0[i4] + bhh0[i4];
        else if (i4 < 256) { int i = i4 - 128; bias1[i] = bih1[i] + bhh1[i]; }
        else if (i4 < 272) {
            int i = i4 - 256;
            biash[i] = (i < 10) ? bcls[i] : ((i < 12) ? bact[i - 10] : 0.f);
        } else if (i4 < 336) {
            ((float*)(ws + ZERO_OFF))[i4 - 272] = 0.f;
        }
    }
}

// ============ kernel 2: fused — async-stage everything, then MFMA ============
// LDS: stage [16][452] f32 (crop in crop-order; k>=400 zeros)  28928 B
//      h0st  [16 granules][64 lanes][4 f32] fragment-ordered    16384 B
//      h1ex  [16][136] bf16                                      4352 B
//      h2ex aliases stage (crop dead after GEMM0 + barrier)
#define STGSTR 452
#define HEXSTR 136

__global__ __launch_bounds__(256) void fused_main(
    const float* __restrict__ image, const int* __restrict__ center,
    const float* __restrict__ h0, const char* __restrict__ ws,
    float* __restrict__ out)
{
    const bf16x8* wp0 = (const bf16x8*)(ws + WP0_OFF);
    const bf16x8* wp1 = (const bf16x8*)(ws + WP1_OFF);
    const bf16x8* wph = (const bf16x8*)(ws + WPH_OFF);
    const float* bias0 = (const float*)(ws + BIAS0_OFF);
    const float* bias1 = (const float*)(ws + BIAS1_OFF);
    const float* biash = (const float*)(ws + BIASH_OFF);
    const float* zbuf  = (const float*)(ws + ZERO_OFF);

    __shared__ __align__(16) float stage[MTILE * STGSTR];
    __shared__ __align__(16) float h0st[16 * 256];
    __shared__ __align__(16) __bf16 h1ex[MTILE * HEXSTR];
    __bf16* h2ex = (__bf16*)stage;    // alias, used after barrier 2

    const int t = threadIdx.x, lane = t & 63, wn = t >> 6;   // 4 waves
    const int m0 = blockIdx.x * MTILE;
    const int l15 = lane & 15, l16 = lane >> 4;

    // ---- phase 0a: h0 async staging (4 granule issues per wave, fragment order) ----
    #pragma unroll
    for (int u = 0; u < 4; ++u) {
        int c = wn * 4 + u;                      // combo 0..15: L(1) s(2) half(1)
        int L = c >> 3, s = (c >> 1) & 3, half = c & 1;
        const float* src = h0 + (size_t)L * B_TOT * 128
                         + (size_t)(m0 + l15) * 128 + s * 32 + l16 * 8 + half * 4;
        gl_lds16(src, &h0st[c * 256]);
    }

    // ---- phase 0b: centers (wave-uniform scalar loads) ----
    const int s0 = wn * 4;
    int cxv[4], cyv[4];
    #pragma unroll
    for (int i = 0; i < 4; ++i) {
        cxv[i] = center[(m0 + s0 + i) * 2 + 0];
        cyv[i] = center[(m0 + s0 + i) * 2 + 1];
    }

    // ---- phase 0c: crop async staging, per-lane gather addresses ----
    {
        int k = lane;
        int r = k / 20, c = k - r * 20;          // lane-constant start
        #pragma unroll
        for (int j = 0; j < 7; ++j) {
            #pragma unroll
            for (int i = 0; i < 4; ++i) {
                int iy = cyv[i] - 20 + r;
                int ix = cxv[i] - 20 + c;
                bool ok = ((unsigned)iy < 28u) && ((unsigned)ix < 28u) && (k < 400);
                const float* src = ok ? (image + (size_t)(m0 + s0 + i) * 784 + iy * 28 + ix)
                                      : zbuf;
                gl_lds4(src, &stage[(s0 + i) * STGSTR + j * 64]);
            }
            k += 64;
            c += 4; if (c >= 20) { c -= 20; r += 4; } else { r += 3; }
        }
    }
    __syncthreads();   // barrier 1: drains all async stages (vmcnt 0)

    // ================= GEMMs: wave wn owns 32 output cols (cg = wn) =================
    const int cg = wn;
    const int qr = l16, lr = l15;
    const float* stg = stage + lr * STGSTR;

    float* outh1 = out + (size_t)B_TOT * 12;
    float* outh2 = out + (size_t)B_TOT * 140;

    // GEMM0: crop ksteps 0..12 (LDS f32 -> cvt) + h0_0 ksteps 13..16 (frag-ordered LDS)
    f32x4 acc0[2] = {};
    #pragma unroll
    for (int s = 0; s < 13; ++s) {
        f32x4 fa = *(const f32x4*)(stg + s * 32 + qr * 8);
        f32x4 fb = *(const f32x4*)(stg + s * 32 + qr * 8 + 4);
        bf16x8 a = cvt8(fa, fb);
        bf16x8 b0 = wp0[(size_t)(s * 8 + cg * 2 + 0) * 64 + lane];
        bf16x8 b1 = wp0[(size_t)(s * 8 + cg * 2 + 1) * 64 + lane];
        acc0[0] = __builtin_amdgcn_mfma_f32_16x16x32_bf16(a, b0, acc0[0], 0, 0, 0);
        acc0[1] = __builtin_amdgcn_mfma_f32_16x16x32_bf16(a, b1, acc0[1], 0, 0, 0);
    }
    #pragma unroll
    for (int s = 0; s < 4; ++s) {
        f32x4 fa = *(const f32x4*)(h0st + (s * 2 + 0) * 256 + lane * 4);
        f32x4 fb = *(const f32x4*)(h0st + (s * 2 + 1) * 256 + lane * 4);
        bf16x8 a = cvt8(fa, fb);
        bf16x8 b0 = wp0[(size_t)((13 + s) * 8 + cg * 2 + 0) * 64 + lane];
        bf16x8 b1 = wp0[(size_t)((13 + s) * 8 + cg * 2 + 1) * 64 + lane];
        acc0[0] = __builtin_amdgcn_mfma_f32_16x16x32_bf16(a, b0, acc0[0], 0, 0, 0);
        acc0[1] = __builtin_amdgcn_mfma_f32_16x16x32_bf16(a, b1, acc0[1], 0, 0, 0);
    }
    #pragma unroll
    for (int f = 0; f < 2; ++f) {
        int n = cg * 32 + f * 16 + lr;
        float bv = bias0[n];
        #pragma unroll
        for (int r = 0; r < 4; ++r)
            h1ex[(qr * 4 + r) * HEXSTR + n] = (__bf16)fast_tanh(acc0[f][r] + bv);
    }

    // GEMM1 part A: h0_1 (ksteps 4..7) — independent of h1
    f32x4 acc1[2] = {};
    #pragma unroll
    for (int s = 0; s < 4; ++s) {
        f32x4 fa = *(const f32x4*)(h0st + (8 + s * 2 + 0) * 256 + lane * 4);
        f32x4 fb = *(const f32x4*)(h0st + (8 + s * 2 + 1) * 256 + lane * 4);
        bf16x8 a = cvt8(fa, fb);
        bf16x8 b0 = wp1[(size_t)((4 + s) * 8 + cg * 2 + 0) * 64 + lane];
        bf16x8 b1 = wp1[(size_t)((4 + s) * 8 + cg * 2 + 1) * 64 + lane];
        acc1[0] = __builtin_amdgcn_mfma_f32_16x16x32_bf16(a, b0, acc1[0], 0, 0, 0);
        acc1[1] = __builtin_amdgcn_mfma_f32_16x16x32_bf16(a, b1, acc1[1], 0, 0, 0);
    }
    __syncthreads();   // barrier 2: h1ex ready; crop stage now dead

    // h1 full-line out stores
    {
        int row = t >> 4, c0 = (t & 15) * 8;
        bf16x8 hv = *(const bf16x8*)(h1ex + row * HEXSTR + c0);
        float4 o1, o2;
        o1.x=(float)hv[0]; o1.y=(float)hv[1]; o1.z=(float)hv[2]; o1.w=(float)hv[3];
        o2.x=(float)hv[4]; o2.y=(float)hv[5]; o2.z=(float)hv[6]; o2.w=(float)hv[7];
        *(float4*)(outh1 + (size_t)(m0 + row) * 128 + c0) = o1;
        *(float4*)(outh1 + (size_t)(m0 + row) * 128 + c0 + 4) = o2;
    }

    // GEMM1 part B: h1 (ksteps 0..3) from LDS bf16
    {
        const __bf16* h1row = h1ex + lr * HEXSTR + qr * 8;
        #pragma unroll
        for (int s = 0; s < 4; ++s) {
            bf16x8 a  = *(const bf16x8*)(h1row + s * 32);
            bf16x8 b0 = wp1[(size_t)(s * 8 + cg * 2 + 0) * 64 + lane];
            bf16x8 b1 = wp1[(size_t)(s * 8 + cg * 2 + 1) * 64 + lane];
            acc1[0] = __builtin_amdgcn_mfma_f32_16x16x32_bf16(a, b0, acc1[0], 0, 0, 0);
            acc1[1] = __builtin_amdgcn_mfma_f32_16x16x32_bf16(a, b1, acc1[1], 0, 0, 0);
        }
    }
    #pragma unroll
    for (int f = 0; f < 2; ++f) {
        int n = cg * 32 + f * 16 + lr;
        float bv = bias1[n];
        #pragma unroll
        for (int r = 0; r < 4; ++r)
            h2ex[(qr * 4 + r) * HEXSTR + n] = (__bf16)fast_tanh(acc1[f][r] + bv);
    }
    __syncthreads();   // barrier 3: h2ex ready

    // h2 full-line out stores
    {
        int row = t >> 4, c0 = (t & 15) * 8;
        bf16x8 hv = *(const bf16x8*)(h2ex + row * HEXSTR + c0);
        float4 o1, o2;
        o1.x=(float)hv[0]; o1.y=(float)hv[1]; o1.z=(float)hv[2]; o1.w=(float)hv[3];
        o2.x=(float)hv[4]; o2.y=(float)hv[5]; o2.z=(float)hv[6]; o2.w=(float)hv[7];
        *(float4*)(outh2 + (size_t)(m0 + row) * 128 + c0) = o1;
        *(float4*)(outh2 + (size_t)(m0 + row) * 128 + c0 + 4) = o2;
    }

    // heads (wave 0): N padded to 16
    if (cg == 0) {
        f32x4 acc2 = {};
        const __bf16* h2row = h2ex + lr * HEXSTR + qr * 8;
        #pragma unroll
        for (int s = 0; s < 4; ++s) {
            bf16x8 a = *(const bf16x8*)(h2row + s * 32);
            bf16x8 b = wph[(size_t)s * 64 + lane];
            acc2 = __builtin_amdgcn_mfma_f32_16x16x32_bf16(a, b, acc2, 0, 0, 0);
        }
        float bhd = biash[lr];
        #pragma unroll
        for (int r = 0; r < 4; ++r) {
            int mg = m0 + qr * 4 + r;
            float v = acc2[r] + bhd;
            if (lr < 10)      out[(size_t)mg * 10 + lr] = v;
            else if (lr < 12) out[(size_t)B_TOT * 10 + (size_t)mg * 2 + (lr - 10)] = v;
        }
    }
}

extern "C" void kernel_launch(void* const* d_in, const int* in_sizes, int n_in,
                              void* d_out, int out_size, void* d_ws, size_t ws_size,
                              hipStream_t stream) {
    const float* image = (const float*)d_in[0];
    const int*   center = (const int*)d_in[1];
    const float* h0   = (const float*)d_in[2];
    const float* Wih0 = (const float*)d_in[3];
    const float* bih0 = (const float*)d_in[4];
    const float* Whh0 = (const float*)d_in[5];
    const float* bhh0 = (const float*)d_in[6];
    const float* Wih1 = (const float*)d_in[7];
    const float* bih1 = (const float*)d_in[8];
    const float* Whh1 = (const float*)d_in[9];
    const float* bhh1 = (const float*)d_in[10];
    const float* Wcls = (const float*)d_in[11];
    const float* bcls = (const float*)d_in[12];
    const float* Wact = (const float*)d_in[13];
    const float* bact = (const float*)d_in[14];

    prepack_kernel<<<PREP_BLOCKS, 256, 0, stream>>>(
        Wih0, Whh0, Wih1, Whh1, Wcls, Wact,
        bih0, bhh0, bih1, bhh1, bcls, bact, (char*)d_ws);
    fused_main<<<B_TOT / MTILE, 256, 0, stream>>>(
        image, center, h0, (const char*)d_ws, (float*)d_out);
}